// Round 5
// baseline (2149.198 us; speedup 1.0000x reference)
//
#include <hip/hip_runtime.h>
#include <hip/hip_bf16.h>

using bf16 = __hip_bfloat16;

#define B_  64
#define C_  256
#define HD_ 256
#define XS  31
#define XO  29
#define ZS  7
#define ZO  5
#define OSP 25
#define XO2 (XO*XO)    // 841
#define ZO2 (ZO*ZO)    // 25
#define OS2 (OSP*OSP)  // 625
#define EPSF 1e-5f

// ---------------------------------------------------------------------------
// Fused: dw3+BN+ReLU on x-tile and z-tile, then depthwise 5x5 xcorr.
// One block per (b,c). All staging in LDS; writes xcorr [B][C][625] fp32.
// ---------------------------------------------------------------------------
__global__ __launch_bounds__(256) void fused_pre_xcorr(
    const float* __restrict__ x, const float* __restrict__ z,
    const float* __restrict__ w, const float* __restrict__ g,
    const float* __restrict__ bb, const float* __restrict__ mm,
    const float* __restrict__ vv, float* __restrict__ out)
{
    const int bc  = blockIdx.x;
    const int c   = bc & (C_ - 1);
    const int tid = threadIdx.x;

    __shared__ float xt[XS * XS];
    __shared__ float zt[ZS * ZS];
    __shared__ float st[XO2];
    __shared__ float kt[ZO2];
    __shared__ float wt[9];

    const float* xp = x + (size_t)bc * (XS * XS);
    for (int j = tid; j < XS * XS; j += 256) xt[j] = xp[j];
    const float* zp = z + (size_t)bc * (ZS * ZS);
    if (tid < ZS * ZS) zt[tid] = zp[tid];
    if (tid < 9)       wt[tid] = w[c * 9 + tid];
    const float inv  = g[c] * rsqrtf(vv[c] + EPSF);
    const float beta = bb[c] - mm[c] * inv;
    __syncthreads();

    for (int s = tid; s < XO2; s += 256) {
        int oy = s / XO, ox = s - oy * XO;
        float a = 0.f;
        #pragma unroll
        for (int dy = 0; dy < 3; ++dy)
            #pragma unroll
            for (int dx = 0; dx < 3; ++dx)
                a += xt[(oy + dy) * XS + ox + dx] * wt[dy * 3 + dx];
        st[s] = fmaxf(a * inv + beta, 0.f);
    }
    if (tid < ZO2) {
        int oy = tid / ZO, ox = tid - oy * ZO;
        float a = 0.f;
        #pragma unroll
        for (int dy = 0; dy < 3; ++dy)
            #pragma unroll
            for (int dx = 0; dx < 3; ++dx)
                a += zt[(oy + dy) * ZS + ox + dx] * wt[dy * 3 + dx];
        kt[tid] = fmaxf(a * inv + beta, 0.f);
    }
    __syncthreads();

    float* op = out + (size_t)bc * OS2;
    for (int s = tid; s < OS2; s += 256) {
        int u = s / OSP, v2 = s - u * OSP;
        const float* base = &st[u * XO + v2];
        float a = 0.f;
        #pragma unroll
        for (int p = 0; p < 5; ++p)
            #pragma unroll
            for (int q = 0; q < 5; ++q)
                a += base[p * XO + q] * kt[p * 5 + q];
        op[s] = a;
    }
}

// ---------------------------------------------------------------------------
// 1x1 conv as batched GEMM with fused BN+ReLU.
// Out[b][o][s] = relu(bn(sum_c X[b][c][s] * W[o][c]))
// ---------------------------------------------------------------------------
__global__ __launch_bounds__(256) void c1_bn_relu(
    const float* __restrict__ X, const float* __restrict__ W,
    const float* __restrict__ g, const float* __restrict__ bb,
    const float* __restrict__ mm, const float* __restrict__ vv,
    float* __restrict__ out)
{
    __shared__ float lw[32][65];
    __shared__ float lx[32][64];

    const int tid = threadIdx.x;
    const int tx = tid & 15, ty = tid >> 4;
    const int sb = blockIdx.x * 64;
    const int ob = blockIdx.y * 64;
    const int b  = blockIdx.z;
    const float* Xb = X + (size_t)b * C_ * OS2;

    float acc[4][4] = {};

    for (int kk = 0; kk < C_; kk += 32) {
        for (int t = tid; t < 2048; t += 256) {
            int o = t >> 5, k = t & 31;
            lw[k][o] = W[(size_t)(ob + o) * C_ + kk + k];
        }
        for (int t = tid; t < 2048; t += 256) {
            int k = t >> 6, s = t & 63;
            int ss = sb + s;
            lx[k][s] = (ss < OS2) ? Xb[(size_t)(kk + k) * OS2 + ss] : 0.f;
        }
        __syncthreads();
        #pragma unroll
        for (int k = 0; k < 32; ++k) {
            float a0 = lw[k][ty], a1 = lw[k][ty + 16], a2 = lw[k][ty + 32], a3 = lw[k][ty + 48];
            float x0 = lx[k][tx], x1 = lx[k][tx + 16], x2 = lx[k][tx + 32], x3 = lx[k][tx + 48];
            acc[0][0] += a0 * x0; acc[0][1] += a0 * x1; acc[0][2] += a0 * x2; acc[0][3] += a0 * x3;
            acc[1][0] += a1 * x0; acc[1][1] += a1 * x1; acc[1][2] += a1 * x2; acc[1][3] += a1 * x3;
            acc[2][0] += a2 * x0; acc[2][1] += a2 * x1; acc[2][2] += a2 * x2; acc[2][3] += a2 * x3;
            acc[3][0] += a3 * x0; acc[3][1] += a3 * x1; acc[3][2] += a3 * x2; acc[3][3] += a3 * x3;
        }
        __syncthreads();
    }

    #pragma unroll
    for (int i = 0; i < 4; ++i) {
        int o = ob + ty + i * 16;
        float inv  = g[o] * rsqrtf(vv[o] + EPSF);
        float beta = bb[o] - mm[o] * inv;
        #pragma unroll
        for (int j = 0; j < 4; ++j) {
            int s = sb + tx + j * 16;
            if (s < OS2)
                out[((size_t)b * HD_ + o) * OS2 + s] = fmaxf(acc[i][j] * inv + beta, 0.f);
        }
    }
}

// ---------------------------------------------------------------------------
template <int CON>
__global__ __launch_bounds__(256) void w2_accum(
    const float* __restrict__ h, const float* __restrict__ w2,
    const float* __restrict__ b2v, const float* __restrict__ wv,
    int si, float* __restrict__ oacc)
{
    __shared__ float lw[CON * C_];
    const int b = blockIdx.x;
    const int tid = threadIdx.x;
    for (int t = tid; t < CON * C_; t += 256) lw[t] = w2[t];
    const float e0 = __expf(wv[0]), e1 = __expf(wv[1]), e2 = __expf(wv[2]);
    const float wi = ((si == 0) ? e0 : (si == 1) ? e1 : e2) / (e0 + e1 + e2);
    __syncthreads();

    const int s = blockIdx.y * 256 + tid;
    if (s >= OS2) return;
    const float* hb = h + (size_t)b * C_ * OS2;

    float acc[CON];
    #pragma unroll
    for (int co = 0; co < CON; ++co) acc[co] = b2v[co];
    for (int c = 0; c < C_; ++c) {
        float hv = hb[(size_t)c * OS2 + s];
        #pragma unroll
        for (int co = 0; co < CON; ++co) acc[co] += hv * lw[co * C_ + c];
    }
    #pragma unroll
    for (int co = 0; co < CON; ++co)
        oacc[((size_t)b * CON + co) * OS2 + s] += wi * acc[co];
}

// FP32 output copy — reference output dtype is float32, so d_out is float*.
__global__ void to_f32_k(const float* __restrict__ in, float* __restrict__ out, int n)
{
    int i = blockIdx.x * 256 + threadIdx.x;
    if (i < n) out[i] = in[i];
}

__global__ void fillf_k(float* __restrict__ out, int n, float v)
{
    int i = blockIdx.x * 256 + threadIdx.x;
    if (i < n) out[i] = v;
}

// ===========================================================================
extern "C" void kernel_launch(void* const* d_in, const int* in_sizes, int n_in,
                              void* d_out, int out_size, void* d_ws, size_t ws_size,
                              hipStream_t stream)
{
    static const int EXP_SIZES[36] = {
        2408448, 47235072, 6912,
        768, 768, 768, 768,
        196608, 768, 768, 768, 768,
        196608, 768, 768, 768, 768, 1536, 6,
        196608, 768, 768, 768, 768, 3072, 12,
        196608, 768, 768, 768, 768, 768, 3,
        3, 3, 3
    };
    int bad = -1;
    if (n_in != 36) bad = 99;
    else {
        for (int i = 0; i < 36; ++i)
            if (in_sizes[i] != EXP_SIZES[i]) { bad = i; break; }
    }
    if (bad < 0 && ws_size < (size_t)83040000) bad = 90;
    if (bad < 0 && out_size != 280000) bad = 95;
    if (bad >= 0) {
        fillf_k<<<(out_size + 255) / 256, 256, 0, stream>>>(
            (float*)d_out, out_size, 500.f + 4.f * bad);
        return;
    }

    const float* z_fs   = (const float*)d_in[0];
    const float* x_fs   = (const float*)d_in[1];
    const float* pre_w  = (const float*)d_in[2];
    const float* pre_g  = (const float*)d_in[3];
    const float* pre_b  = (const float*)d_in[4];
    const float* pre_m  = (const float*)d_in[5];
    const float* pre_v  = (const float*)d_in[6];
    const float* head_w = (const float*)d_in[7];
    const float* head_g = (const float*)d_in[8];
    const float* head_b = (const float*)d_in[9];
    const float* head_m = (const float*)d_in[10];
    const float* head_v = (const float*)d_in[11];
    const float* cls_w1 = (const float*)d_in[12];
    const float* cls_g  = (const float*)d_in[13];
    const float* cls_b  = (const float*)d_in[14];
    const float* cls_m  = (const float*)d_in[15];
    const float* cls_v  = (const float*)d_in[16];
    const float* cls_w2 = (const float*)d_in[17];
    const float* cls_b2 = (const float*)d_in[18];
    const float* loc_w1 = (const float*)d_in[19];
    const float* loc_g  = (const float*)d_in[20];
    const float* loc_b  = (const float*)d_in[21];
    const float* loc_m  = (const float*)d_in[22];
    const float* loc_v  = (const float*)d_in[23];
    const float* loc_w2 = (const float*)d_in[24];
    const float* loc_b2 = (const float*)d_in[25];
    const float* ctr_w1 = (const float*)d_in[26];
    const float* ctr_g  = (const float*)d_in[27];
    const float* ctr_b  = (const float*)d_in[28];
    const float* ctr_m  = (const float*)d_in[29];
    const float* ctr_v  = (const float*)d_in[30];
    const float* ctr_w2 = (const float*)d_in[31];
    const float* ctr_b2 = (const float*)d_in[32];
    const float* w_cls  = (const float*)d_in[33];
    const float* w_loc  = (const float*)d_in[34];
    const float* w_ctr  = (const float*)d_in[35];

    float* xc   = (float*)d_ws;
    float* feat = xc + (size_t)B_ * C_ * OS2;      // +10,240,000 floats
    float* acc  = feat + (size_t)B_ * HD_ * OS2;   // +10,240,000 floats
    const int OUT_N = B_ * (2 + 4 + 1) * OS2;       // 280,000

    hipMemsetAsync(acc, 0, (size_t)OUT_N * sizeof(float), stream);

    const dim3 gemm_grid(10, 4, B_);

    for (int i = 0; i < 3; ++i) {
        fused_pre_xcorr<<<B_ * C_, 256, 0, stream>>>(
            x_fs + (size_t)i * B_ * C_ * XS * XS,
            z_fs + (size_t)i * B_ * C_ * ZS * ZS,
            pre_w + (size_t)i * C_ * 9,
            pre_g + i * C_, pre_b + i * C_, pre_m + i * C_, pre_v + i * C_,
            xc);

        c1_bn_relu<<<gemm_grid, 256, 0, stream>>>(
            xc, head_w + (size_t)i * HD_ * C_,
            head_g + i * HD_, head_b + i * HD_, head_m + i * HD_, head_v + i * HD_,
            feat);

        // cls
        c1_bn_relu<<<gemm_grid, 256, 0, stream>>>(
            feat, cls_w1 + (size_t)i * HD_ * HD_,
            cls_g + i * HD_, cls_b + i * HD_, cls_m + i * HD_, cls_v + i * HD_,
            xc);
        w2_accum<2><<<dim3(B_, 3), 256, 0, stream>>>(
            xc, cls_w2 + (size_t)i * 2 * HD_, cls_b2 + i * 2, w_cls, i, acc + 0);

        // loc
        c1_bn_relu<<<gemm_grid, 256, 0, stream>>>(
            feat, loc_w1 + (size_t)i * HD_ * HD_,
            loc_g + i * HD_, loc_b + i * HD_, loc_m + i * HD_, loc_v + i * HD_,
            xc);
        w2_accum<4><<<dim3(B_, 3), 256, 0, stream>>>(
            xc, loc_w2 + (size_t)i * 4 * HD_, loc_b2 + i * 4, w_loc, i,
            acc + B_ * 2 * OS2);

        // ctr
        c1_bn_relu<<<gemm_grid, 256, 0, stream>>>(
            feat, ctr_w1 + (size_t)i * HD_ * HD_,
            ctr_g + i * HD_, ctr_b + i * HD_, ctr_m + i * HD_, ctr_v + i * HD_,
            xc);
        w2_accum<1><<<dim3(B_, 3), 256, 0, stream>>>(
            xc, ctr_w2 + (size_t)i * 1 * HD_, ctr_b2 + i * 1, w_ctr, i,
            acc + B_ * 6 * OS2);
    }

    to_f32_k<<<(OUT_N + 255) / 256, 256, 0, stream>>>(acc, (float*)d_out, OUT_N);
}

// Round 6
// 891.669 us; speedup vs baseline: 2.4103x; 2.4103x over previous
//
#include <hip/hip_runtime.h>
#include <hip/hip_bf16.h>

using bf16 = __hip_bfloat16;

#define B_  64
#define C_  256
#define HD_ 256
#define XS  31
#define XO  29
#define ZS  7
#define ZO  5
#define OSP 25
#define XO2 (XO*XO)    // 841
#define ZO2 (ZO*ZO)    // 25
#define OS2 (OSP*OSP)  // 625
#define EPSF 1e-5f

typedef __attribute__((ext_vector_type(4))) float f32x4;
typedef __attribute__((ext_vector_type(8))) short s16x8;

__device__ __forceinline__ unsigned short f2bf(float f) {
    union { float f; unsigned int u; } a; a.f = f;
    unsigned int r = a.u + 0x7FFF + ((a.u >> 16) & 1);   // RNE
    return (unsigned short)(r >> 16);
}
__device__ __forceinline__ float bf2f(unsigned short u) {
    union { unsigned int u; float f; } a; a.u = ((unsigned int)u) << 16;
    return a.f;
}
__device__ __forceinline__ unsigned int pk2(unsigned short a, unsigned short b) {
    return (unsigned int)a | ((unsigned int)b << 16);
}
__device__ __forceinline__ void stout(float* p, float v)         { *p = v; }
__device__ __forceinline__ void stout(unsigned short* p, float v){ *p = f2bf(v); }

// ---------------------------------------------------------------------------
// Fused: dw3+BN+ReLU on x-tile and z-tile, then depthwise 5x5 xcorr.
// One block per (b,c). Writes xcorr [B][C][625] as bf16.
// ---------------------------------------------------------------------------
__global__ __launch_bounds__(256) void fused_pre_xcorr(
    const float* __restrict__ x, const float* __restrict__ z,
    const float* __restrict__ w, const float* __restrict__ g,
    const float* __restrict__ bb, const float* __restrict__ mm,
    const float* __restrict__ vv, unsigned short* __restrict__ out)
{
    const int bc  = blockIdx.x;
    const int c   = bc & (C_ - 1);
    const int tid = threadIdx.x;

    __shared__ float xt[XS * XS];
    __shared__ float zt[ZS * ZS];
    __shared__ float st[XO2];
    __shared__ float kt[ZO2];
    __shared__ float wt[9];

    const float* xp = x + (size_t)bc * (XS * XS);
    for (int j = tid; j < XS * XS; j += 256) xt[j] = xp[j];
    const float* zp = z + (size_t)bc * (ZS * ZS);
    if (tid < ZS * ZS) zt[tid] = zp[tid];
    if (tid < 9)       wt[tid] = w[c * 9 + tid];
    const float inv  = g[c] * rsqrtf(vv[c] + EPSF);
    const float beta = bb[c] - mm[c] * inv;
    __syncthreads();

    for (int s = tid; s < XO2; s += 256) {
        int oy = s / XO, ox = s - oy * XO;
        float a = 0.f;
        #pragma unroll
        for (int dy = 0; dy < 3; ++dy)
            #pragma unroll
            for (int dx = 0; dx < 3; ++dx)
                a += xt[(oy + dy) * XS + ox + dx] * wt[dy * 3 + dx];
        st[s] = fmaxf(a * inv + beta, 0.f);
    }
    if (tid < ZO2) {
        int oy = tid / ZO, ox = tid - oy * ZO;
        float a = 0.f;
        #pragma unroll
        for (int dy = 0; dy < 3; ++dy)
            #pragma unroll
            for (int dx = 0; dx < 3; ++dx)
                a += zt[(oy + dy) * ZS + ox + dx] * wt[dy * 3 + dx];
        kt[tid] = fmaxf(a * inv + beta, 0.f);
    }
    __syncthreads();

    unsigned short* op = out + (size_t)bc * OS2;
    for (int s = tid; s < OS2; s += 256) {
        int u = s / OSP, v2 = s - u * OSP;
        const float* base = &st[u * XO + v2];
        float a = 0.f;
        #pragma unroll
        for (int p = 0; p < 5; ++p)
            #pragma unroll
            for (int q = 0; q < 5; ++q)
                a += base[p * XO + q] * kt[p * 5 + q];
        op[s] = f2bf(a);
    }
}

// ---------------------------------------------------------------------------
// MFMA 1x1-conv GEMM with fused BN+ReLU.
// out[b][o][s] = relu(bn(sum_c W[o][c] * X[b][c][s]))
// X: bf16 [B][256][625]; W: fp32 [256][256]; out: OutT [B][256][625].
// Block tile 128(o) x 128(s), K-chunks of 32. 256 thr = 4 waves, each wave
// 64x64 via 4x4 grid of 16x16x32 MFMA. LDS tiles fragment-major [quad][row][j]
// so staging writes and fragment reads are both single aligned b128 ops.
// grid = (5, 2, 64).
// ---------------------------------------------------------------------------
template <typename OutT>
__global__ __launch_bounds__(256) void c1_mfma(
    const unsigned short* __restrict__ X,
    const float* __restrict__ W,
    const float* __restrict__ g, const float* __restrict__ bb,
    const float* __restrict__ mm, const float* __restrict__ vv,
    OutT* __restrict__ out)
{
    __shared__ unsigned short Abuf[4 * 128 * 8];   // [quad][m][j] 8 KB
    __shared__ unsigned short Bbuf[4 * 128 * 8];   // [quad][n][j] 8 KB
    __shared__ float s_inv[128], s_beta[128];

    const int tid  = threadIdx.x;
    const int wave = tid >> 6, lane = tid & 63;
    const int quad = lane >> 4, l16 = lane & 15;
    const int sb = blockIdx.x * 128;
    const int ob = blockIdx.y * 128;
    const int b  = blockIdx.z;
    const int wm = (wave & 1) * 64, wn = (wave >> 1) * 64;

    if (tid < 128) {
        int o = ob + tid;
        float iv = g[o] * rsqrtf(vv[o] + EPSF);
        s_inv[tid]  = iv;
        s_beta[tid] = bb[o] - mm[o] * iv;
    }

    const int sm = tid & 127;     // A row m / B row n
    const int kh = tid >> 7;      // k half: k = kh*16 .. +15
    const unsigned short* Xb = X + (size_t)b * C_ * OS2;
    const bool npred = (sb + sm) < OS2;

    f32x4 acc[4][4];
    #pragma unroll
    for (int i = 0; i < 4; ++i)
        #pragma unroll
        for (int j = 0; j < 4; ++j)
            acc[i][j] = (f32x4){0.f, 0.f, 0.f, 0.f};

    for (int kk = 0; kk < C_; kk += 32) {
        // ---- stage A (W, fp32 -> bf16), rows 256 floats = aligned ----
        const float* wp = W + (size_t)(ob + sm) * C_ + kk + kh * 16;
        float4 w0 = *(const float4*)(wp + 0);
        float4 w1 = *(const float4*)(wp + 4);
        float4 w2 = *(const float4*)(wp + 8);
        float4 w3 = *(const float4*)(wp + 12);
        uint4 pa0, pa1;
        pa0.x = pk2(f2bf(w0.x), f2bf(w0.y)); pa0.y = pk2(f2bf(w0.z), f2bf(w0.w));
        pa0.z = pk2(f2bf(w1.x), f2bf(w1.y)); pa0.w = pk2(f2bf(w1.z), f2bf(w1.w));
        pa1.x = pk2(f2bf(w2.x), f2bf(w2.y)); pa1.y = pk2(f2bf(w2.z), f2bf(w2.w));
        pa1.z = pk2(f2bf(w3.x), f2bf(w3.y)); pa1.w = pk2(f2bf(w3.z), f2bf(w3.w));
        *(uint4*)&Abuf[((kh * 2 + 0) * 128 + sm) * 8] = pa0;
        *(uint4*)&Abuf[((kh * 2 + 1) * 128 + sm) * 8] = pa1;

        // ---- stage B (X bf16), 16 coalesced b16 loads along s ----
        unsigned short bu[16];
        #pragma unroll
        for (int j = 0; j < 16; ++j)
            bu[j] = npred ? Xb[(size_t)(kk + kh * 16 + j) * OS2 + sb + sm]
                          : (unsigned short)0;
        uint4 pb0, pb1;
        pb0.x = pk2(bu[0],  bu[1]);  pb0.y = pk2(bu[2],  bu[3]);
        pb0.z = pk2(bu[4],  bu[5]);  pb0.w = pk2(bu[6],  bu[7]);
        pb1.x = pk2(bu[8],  bu[9]);  pb1.y = pk2(bu[10], bu[11]);
        pb1.z = pk2(bu[12], bu[13]); pb1.w = pk2(bu[14], bu[15]);
        *(uint4*)&Bbuf[((kh * 2 + 0) * 128 + sm) * 8] = pb0;
        *(uint4*)&Bbuf[((kh * 2 + 1) * 128 + sm) * 8] = pb1;

        __syncthreads();

        // ---- fragments + MFMA ----
        s16x8 af[4], bfr[4];
        #pragma unroll
        for (int mt = 0; mt < 4; ++mt)
            af[mt] = *(const s16x8*)&Abuf[(quad * 128 + wm + mt * 16 + l16) * 8];
        #pragma unroll
        for (int nt = 0; nt < 4; ++nt)
            bfr[nt] = *(const s16x8*)&Bbuf[(quad * 128 + wn + nt * 16 + l16) * 8];
        #pragma unroll
        for (int mt = 0; mt < 4; ++mt)
            #pragma unroll
            for (int nt = 0; nt < 4; ++nt)
                acc[mt][nt] = __builtin_amdgcn_mfma_f32_16x16x32_bf16(
                    af[mt], bfr[nt], acc[mt][nt], 0, 0, 0);

        __syncthreads();
    }

    // ---- epilogue: BN+ReLU, store ----
    #pragma unroll
    for (int mt = 0; mt < 4; ++mt) {
        #pragma unroll
        for (int r = 0; r < 4; ++r) {
            int orow = wm + mt * 16 + quad * 4 + r;
            float iv = s_inv[orow], be = s_beta[orow];
            size_t obase = ((size_t)b * C_ + (ob + orow)) * OS2;
            #pragma unroll
            for (int nt = 0; nt < 4; ++nt) {
                int s = sb + wn + nt * 16 + l16;
                if (s < OS2)
                    stout(out + obase + s, fmaxf(acc[mt][nt][r] * iv + be, 0.f));
            }
        }
    }
}

// ---------------------------------------------------------------------------
// Final tiny 1x1 (co in {1,2,4}) + bias, softmax(w)[si]-scaled accumulate.
// h is fp32 [B][256][625].
// ---------------------------------------------------------------------------
template <int CON>
__global__ __launch_bounds__(256) void w2_accum(
    const float* __restrict__ h, const float* __restrict__ w2,
    const float* __restrict__ b2v, const float* __restrict__ wv,
    int si, float* __restrict__ oacc)
{
    __shared__ float lw[CON * C_];
    const int b = blockIdx.x;
    const int tid = threadIdx.x;
    for (int t = tid; t < CON * C_; t += 256) lw[t] = w2[t];
    const float e0 = __expf(wv[0]), e1 = __expf(wv[1]), e2 = __expf(wv[2]);
    const float wi = ((si == 0) ? e0 : (si == 1) ? e1 : e2) / (e0 + e1 + e2);
    __syncthreads();

    const int s = blockIdx.y * 256 + tid;
    if (s >= OS2) return;
    const float* hb = h + (size_t)b * C_ * OS2;

    float acc[CON];
    #pragma unroll
    for (int co = 0; co < CON; ++co) acc[co] = b2v[co];
    for (int c = 0; c < C_; ++c) {
        float hv = hb[(size_t)c * OS2 + s];
        #pragma unroll
        for (int co = 0; co < CON; ++co) acc[co] += hv * lw[co * C_ + c];
    }
    #pragma unroll
    for (int co = 0; co < CON; ++co)
        oacc[((size_t)b * CON + co) * OS2 + s] += wi * acc[co];
}

__global__ void to_f32_k(const float* __restrict__ in, float* __restrict__ out, int n)
{
    int i = blockIdx.x * 256 + threadIdx.x;
    if (i < n) out[i] = in[i];
}

__global__ void fillf_k(float* __restrict__ out, int n, float v)
{
    int i = blockIdx.x * 256 + threadIdx.x;
    if (i < n) out[i] = v;
}

// ===========================================================================
extern "C" void kernel_launch(void* const* d_in, const int* in_sizes, int n_in,
                              void* d_out, int out_size, void* d_ws, size_t ws_size,
                              hipStream_t stream)
{
    static const int EXP_SIZES[36] = {
        2408448, 47235072, 6912,
        768, 768, 768, 768,
        196608, 768, 768, 768, 768,
        196608, 768, 768, 768, 768, 1536, 6,
        196608, 768, 768, 768, 768, 3072, 12,
        196608, 768, 768, 768, 768, 768, 3,
        3, 3, 3
    };
    int bad = -1;
    if (n_in != 36) bad = 99;
    else {
        for (int i = 0; i < 36; ++i)
            if (in_sizes[i] != EXP_SIZES[i]) { bad = i; break; }
    }
    if (bad < 0 && ws_size < (size_t)83040000) bad = 90;
    if (bad < 0 && out_size != 280000) bad = 95;
    if (bad >= 0) {
        fillf_k<<<(out_size + 255) / 256, 256, 0, stream>>>(
            (float*)d_out, out_size, 500.f + 4.f * bad);
        return;
    }

    const float* z_fs   = (const float*)d_in[0];
    const float* x_fs   = (const float*)d_in[1];
    const float* pre_w  = (const float*)d_in[2];
    const float* pre_g  = (const float*)d_in[3];
    const float* pre_b  = (const float*)d_in[4];
    const float* pre_m  = (const float*)d_in[5];
    const float* pre_v  = (const float*)d_in[6];
    const float* head_w = (const float*)d_in[7];
    const float* head_g = (const float*)d_in[8];
    const float* head_b = (const float*)d_in[9];
    const float* head_m = (const float*)d_in[10];
    const float* head_v = (const float*)d_in[11];
    const float* cls_w1 = (const float*)d_in[12];
    const float* cls_g  = (const float*)d_in[13];
    const float* cls_b  = (const float*)d_in[14];
    const float* cls_m  = (const float*)d_in[15];
    const float* cls_v  = (const float*)d_in[16];
    const float* cls_w2 = (const float*)d_in[17];
    const float* cls_b2 = (const float*)d_in[18];
    const float* loc_w1 = (const float*)d_in[19];
    const float* loc_g  = (const float*)d_in[20];
    const float* loc_b  = (const float*)d_in[21];
    const float* loc_m  = (const float*)d_in[22];
    const float* loc_v  = (const float*)d_in[23];
    const float* loc_w2 = (const float*)d_in[24];
    const float* loc_b2 = (const float*)d_in[25];
    const float* ctr_w1 = (const float*)d_in[26];
    const float* ctr_g  = (const float*)d_in[27];
    const float* ctr_b  = (const float*)d_in[28];
    const float* ctr_m  = (const float*)d_in[29];
    const float* ctr_v  = (const float*)d_in[30];
    const float* ctr_w2 = (const float*)d_in[31];
    const float* ctr_b2 = (const float*)d_in[32];
    const float* w_cls  = (const float*)d_in[33];
    const float* w_loc  = (const float*)d_in[34];
    const float* w_ctr  = (const float*)d_in[35];

    // workspace: xc bf16 (20.48 MB) | feat bf16 (20.48 MB) | h fp32 (40.96 MB)
    //            | acc fp32 (1.12 MB)  == 83,040,000 B total
    unsigned short* xc   = (unsigned short*)d_ws;
    unsigned short* feat = xc + (size_t)B_ * C_ * OS2;        // +10,240,000 elems
    float* h   = (float*)(feat + (size_t)B_ * C_ * OS2);
    float* acc = h + (size_t)B_ * C_ * OS2;
    const int OUT_N = B_ * (2 + 4 + 1) * OS2;                  // 280,000

    hipMemsetAsync(acc, 0, (size_t)OUT_N * sizeof(float), stream);

    const dim3 mfma_grid(5, 2, B_);

    for (int i = 0; i < 3; ++i) {
        fused_pre_xcorr<<<B_ * C_, 256, 0, stream>>>(
            x_fs + (size_t)i * B_ * C_ * XS * XS,
            z_fs + (size_t)i * B_ * C_ * ZS * ZS,
            pre_w + (size_t)i * C_ * 9,
            pre_g + i * C_, pre_b + i * C_, pre_m + i * C_, pre_v + i * C_,
            xc);

        c1_mfma<unsigned short><<<mfma_grid, 256, 0, stream>>>(
            xc, head_w + (size_t)i * HD_ * C_,
            head_g + i * HD_, head_b + i * HD_, head_m + i * HD_, head_v + i * HD_,
            feat);

        // cls
        c1_mfma<float><<<mfma_grid, 256, 0, stream>>>(
            feat, cls_w1 + (size_t)i * HD_ * HD_,
            cls_g + i * HD_, cls_b + i * HD_, cls_m + i * HD_, cls_v + i * HD_,
            h);
        w2_accum<2><<<dim3(B_, 3), 256, 0, stream>>>(
            h, cls_w2 + (size_t)i * 2 * HD_, cls_b2 + i * 2, w_cls, i, acc + 0);

        // loc
        c1_mfma<float><<<mfma_grid, 256, 0, stream>>>(
            feat, loc_w1 + (size_t)i * HD_ * HD_,
            loc_g + i * HD_, loc_b + i * HD_, loc_m + i * HD_, loc_v + i * HD_,
            h);
        w2_accum<4><<<dim3(B_, 3), 256, 0, stream>>>(
            h, loc_w2 + (size_t)i * 4 * HD_, loc_b2 + i * 4, w_loc, i,
            acc + B_ * 2 * OS2);

        // ctr
        c1_mfma<float><<<mfma_grid, 256, 0, stream>>>(
            feat, ctr_w1 + (size_t)i * HD_ * HD_,
            ctr_g + i * HD_, ctr_b + i * HD_, ctr_m + i * HD_, ctr_v + i * HD_,
            h);
        w2_accum<1><<<dim3(B_, 3), 256, 0, stream>>>(
            h, ctr_w2 + (size_t)i * 1 * HD_, ctr_b2 + i * 1, w_ctr, i,
            acc + B_ * 6 * OS2);
    }

    to_f32_k<<<(OUT_N + 255) / 256, 256, 0, stream>>>(acc, (float*)d_out, OUT_N);
}

// Round 7
// 727.491 us; speedup vs baseline: 2.9543x; 1.2257x over previous
//
#include <hip/hip_runtime.h>
#include <hip/hip_bf16.h>

using bf16 = __hip_bfloat16;

#define B_  64
#define C_  256
#define HD_ 256
#define XS  31
#define XO  29
#define ZS  7
#define ZO  5
#define OSP 25
#define XO2 (XO*XO)    // 841
#define ZO2 (ZO*ZO)    // 25
#define OS2 (OSP*OSP)  // 625
#define EPSF 1e-5f

typedef __attribute__((ext_vector_type(4))) float f32x4;
typedef __attribute__((ext_vector_type(8))) short s16x8;

__device__ __forceinline__ unsigned short f2bf(float f) {
    union { float f; unsigned int u; } a; a.f = f;
    unsigned int r = a.u + 0x7FFF + ((a.u >> 16) & 1);   // RNE
    return (unsigned short)(r >> 16);
}
__device__ __forceinline__ unsigned int pk2(unsigned short a, unsigned short b) {
    return (unsigned int)a | ((unsigned int)b << 16);
}

// ---------------------------------------------------------------------------
// Fused: dw3+BN+ReLU on x-tile and z-tile, then depthwise 5x5 xcorr.
// One block per (b,c). Writes xcorr [B][C][625] as bf16.
// v2: weights + xcorr kernel in REGISTERS; row-shared st reads.
//   ds-inst per block ~3.5x lower than v1 (was the bottleneck).
// ---------------------------------------------------------------------------
__global__ __launch_bounds__(256) void fused_pre_xcorr(
    const float* __restrict__ x, const float* __restrict__ z,
    const float* __restrict__ w, const float* __restrict__ g,
    const float* __restrict__ bb, const float* __restrict__ mm,
    const float* __restrict__ vv, unsigned short* __restrict__ out)
{
    const int bc  = blockIdx.x;
    const int c   = bc & (C_ - 1);
    const int tid = threadIdx.x;

    __shared__ float xt[32 * 32];   // x tile, row stride 32 (+pad row for OOB-safe reads)
    __shared__ float st[29 * 32];   // search feature, row stride 32
    __shared__ float zt[49];
    __shared__ float ktl[25];
    __shared__ float wtl[9];

    const float* xp = x + (size_t)bc * (XS * XS);
    for (int j = tid; j < XS * XS; j += 256) xt[(j / 31) * 32 + (j % 31)] = xp[j];
    if (tid < 49) zt[tid] = z[(size_t)bc * 49 + tid];
    if (tid < 9)  wtl[tid] = w[c * 9 + tid];
    const float inv  = g[c] * rsqrtf(vv[c] + EPSF);
    const float beta = bb[c] - mm[c] * inv;
    __syncthreads();

    float wr[9];
    #pragma unroll
    for (int j = 0; j < 9; ++j) wr[j] = wtl[j];

    // kernel features (5x5), threads 0..24
    if (tid < 25) {
        int oy = tid / 5, ox = tid - (tid / 5) * 5;
        float a = 0.f;
        #pragma unroll
        for (int dy = 0; dy < 3; ++dy)
            #pragma unroll
            for (int dx = 0; dx < 3; ++dx)
                a += zt[(oy + dy) * ZS + ox + dx] * wr[dy * 3 + dx];
        ktl[tid] = fmaxf(a * inv + beta, 0.f);
    }

    // search features: 29 rows x 8 col-groups of 4; threads 0..231
    if (tid < 232) {
        int r = tid >> 3, c0 = (tid & 7) * 4;
        float o0 = 0.f, o1 = 0.f, o2 = 0.f, o3 = 0.f;
        #pragma unroll
        for (int dy = 0; dy < 3; ++dy) {
            const float* row = &xt[(r + dy) * 32 + c0];
            float v0 = row[0], v1 = row[1], v2 = row[2],
                  v3 = row[3], v4 = row[4], v5 = row[5];
            float w0 = wr[dy * 3], w1 = wr[dy * 3 + 1], w2 = wr[dy * 3 + 2];
            o0 += v0 * w0 + v1 * w1 + v2 * w2;
            o1 += v1 * w0 + v2 * w1 + v3 * w2;
            o2 += v2 * w0 + v3 * w1 + v4 * w2;
            o3 += v3 * w0 + v4 * w1 + v5 * w2;
        }
        float4 res;
        res.x = fmaxf(o0 * inv + beta, 0.f);
        res.y = fmaxf(o1 * inv + beta, 0.f);
        res.z = fmaxf(o2 * inv + beta, 0.f);
        res.w = fmaxf(o3 * inv + beta, 0.f);
        *(float4*)&st[r * 32 + c0] = res;   // cols >=29 land in pad, never read
    }
    __syncthreads();

    // xcorr: threads 0..124, each computes 5 consecutive outputs of one row
    if (tid < 125) {
        float kt[25];
        #pragma unroll
        for (int j = 0; j < 25; ++j) kt[j] = ktl[j];
        int u = tid / 5, v0 = (tid - (tid / 5) * 5) * 5;
        float o0 = 0.f, o1 = 0.f, o2 = 0.f, o3 = 0.f, o4 = 0.f;
        #pragma unroll
        for (int p = 0; p < 5; ++p) {
            const float* row = &st[(u + p) * 32 + v0];
            float r0 = row[0], r1 = row[1], r2 = row[2], r3 = row[3], r4 = row[4],
                  r5 = row[5], r6 = row[6], r7 = row[7], r8 = row[8];
            float k0 = kt[p * 5], k1 = kt[p * 5 + 1], k2 = kt[p * 5 + 2],
                  k3 = kt[p * 5 + 3], k4 = kt[p * 5 + 4];
            o0 += r0 * k0 + r1 * k1 + r2 * k2 + r3 * k3 + r4 * k4;
            o1 += r1 * k0 + r2 * k1 + r3 * k2 + r4 * k3 + r5 * k4;
            o2 += r2 * k0 + r3 * k1 + r4 * k2 + r5 * k3 + r6 * k4;
            o3 += r3 * k0 + r4 * k1 + r5 * k2 + r6 * k3 + r7 * k4;
            o4 += r4 * k0 + r5 * k1 + r6 * k2 + r7 * k3 + r8 * k4;
        }
        unsigned short* op = out + (size_t)bc * OS2 + u * OSP + v0;
        op[0] = f2bf(o0); op[1] = f2bf(o1); op[2] = f2bf(o2);
        op[3] = f2bf(o3); op[4] = f2bf(o4);
    }
}

// ---------------------------------------------------------------------------
// Head GEMM: feat[b][o][s] = relu(bn(sum_c W[o][c] * X[b][c][s])), bf16 out.
// Block tile 128x128, K-chunks of 32, 4 waves, 16x16x32 MFMA. grid (5,2,64).
// ---------------------------------------------------------------------------
__global__ __launch_bounds__(256) void c1_mfma(
    const unsigned short* __restrict__ X,
    const float* __restrict__ W,
    const float* __restrict__ g, const float* __restrict__ bb,
    const float* __restrict__ mm, const float* __restrict__ vv,
    unsigned short* __restrict__ out)
{
    __shared__ unsigned short Abuf[4 * 128 * 8];
    __shared__ unsigned short Bbuf[4 * 128 * 8];
    __shared__ float s_inv[128], s_beta[128];

    const int tid  = threadIdx.x;
    const int wave = tid >> 6, lane = tid & 63;
    const int quad = lane >> 4, l16 = lane & 15;
    const int sb = blockIdx.x * 128;
    const int ob = blockIdx.y * 128;
    const int b  = blockIdx.z;
    const int wm = (wave & 1) * 64, wn = (wave >> 1) * 64;

    if (tid < 128) {
        int o = ob + tid;
        float iv = g[o] * rsqrtf(vv[o] + EPSF);
        s_inv[tid]  = iv;
        s_beta[tid] = bb[o] - mm[o] * iv;
    }

    const int sm = tid & 127;
    const int kh = tid >> 7;
    const unsigned short* Xb = X + (size_t)b * C_ * OS2;
    const bool npred = (sb + sm) < OS2;

    f32x4 acc[4][4];
    #pragma unroll
    for (int i = 0; i < 4; ++i)
        #pragma unroll
        for (int j = 0; j < 4; ++j)
            acc[i][j] = (f32x4){0.f, 0.f, 0.f, 0.f};

    for (int kk = 0; kk < C_; kk += 32) {
        const float* wp = W + (size_t)(ob + sm) * C_ + kk + kh * 16;
        float4 w0 = *(const float4*)(wp + 0);
        float4 w1 = *(const float4*)(wp + 4);
        float4 w2 = *(const float4*)(wp + 8);
        float4 w3 = *(const float4*)(wp + 12);
        uint4 pa0, pa1;
        pa0.x = pk2(f2bf(w0.x), f2bf(w0.y)); pa0.y = pk2(f2bf(w0.z), f2bf(w0.w));
        pa0.z = pk2(f2bf(w1.x), f2bf(w1.y)); pa0.w = pk2(f2bf(w1.z), f2bf(w1.w));
        pa1.x = pk2(f2bf(w2.x), f2bf(w2.y)); pa1.y = pk2(f2bf(w2.z), f2bf(w2.w));
        pa1.z = pk2(f2bf(w3.x), f2bf(w3.y)); pa1.w = pk2(f2bf(w3.z), f2bf(w3.w));
        *(uint4*)&Abuf[((kh * 2 + 0) * 128 + sm) * 8] = pa0;
        *(uint4*)&Abuf[((kh * 2 + 1) * 128 + sm) * 8] = pa1;

        unsigned short bu[16];
        #pragma unroll
        for (int j = 0; j < 16; ++j)
            bu[j] = npred ? Xb[(size_t)(kk + kh * 16 + j) * OS2 + sb + sm]
                          : (unsigned short)0;
        uint4 pb0, pb1;
        pb0.x = pk2(bu[0],  bu[1]);  pb0.y = pk2(bu[2],  bu[3]);
        pb0.z = pk2(bu[4],  bu[5]);  pb0.w = pk2(bu[6],  bu[7]);
        pb1.x = pk2(bu[8],  bu[9]);  pb1.y = pk2(bu[10], bu[11]);
        pb1.z = pk2(bu[12], bu[13]); pb1.w = pk2(bu[14], bu[15]);
        *(uint4*)&Bbuf[((kh * 2 + 0) * 128 + sm) * 8] = pb0;
        *(uint4*)&Bbuf[((kh * 2 + 1) * 128 + sm) * 8] = pb1;

        __syncthreads();

        s16x8 af[4], bfr[4];
        #pragma unroll
        for (int mt = 0; mt < 4; ++mt)
            af[mt] = *(const s16x8*)&Abuf[(quad * 128 + wm + mt * 16 + l16) * 8];
        #pragma unroll
        for (int nt = 0; nt < 4; ++nt)
            bfr[nt] = *(const s16x8*)&Bbuf[(quad * 128 + wn + nt * 16 + l16) * 8];
        #pragma unroll
        for (int mt = 0; mt < 4; ++mt)
            #pragma unroll
            for (int nt = 0; nt < 4; ++nt)
                acc[mt][nt] = __builtin_amdgcn_mfma_f32_16x16x32_bf16(
                    af[mt], bfr[nt], acc[mt][nt], 0, 0, 0);

        __syncthreads();
    }

    #pragma unroll
    for (int mt = 0; mt < 4; ++mt) {
        #pragma unroll
        for (int r = 0; r < 4; ++r) {
            int orow = wm + mt * 16 + quad * 4 + r;
            float iv = s_inv[orow], be = s_beta[orow];
            size_t obase = ((size_t)b * HD_ + (ob + orow)) * OS2;
            #pragma unroll
            for (int nt = 0; nt < 4; ++nt) {
                int s = sb + wn + nt * 16 + l16;
                if (s < OS2)
                    out[obase + s] = f2bf(fmaxf(acc[mt][nt][r] * iv + be, 0.f));
            }
        }
    }
}

// ---------------------------------------------------------------------------
// Fused 3-head hidden GEMM + w2 projection + softmax-weighted accumulate.
// grid (5 s-tiles, 6 o-tiles [cls,cls,loc,loc,ctr,ctr], 64 b).
// Epilogue: BN+ReLU in-register, dot with w2 (LDS), quad shuffle-reduce,
// atomicAdd into d_out (fp32, pre-zeroed). h is never materialized.
// ---------------------------------------------------------------------------
__global__ __launch_bounds__(256) void heads3_mfma(
    const unsigned short* __restrict__ feat,
    const float* __restrict__ w1c, const float* __restrict__ w1l, const float* __restrict__ w1t,
    const float* __restrict__ gc, const float* __restrict__ bc2, const float* __restrict__ mc, const float* __restrict__ vc,
    const float* __restrict__ gl, const float* __restrict__ bl, const float* __restrict__ ml, const float* __restrict__ vl,
    const float* __restrict__ gt, const float* __restrict__ bt, const float* __restrict__ mt2, const float* __restrict__ vt,
    const float* __restrict__ w2c, const float* __restrict__ w2l, const float* __restrict__ w2t,
    const float* __restrict__ wvc, const float* __restrict__ wvl, const float* __restrict__ wvt,
    int si, float* __restrict__ oacc)
{
    __shared__ unsigned short Abuf[4 * 128 * 8];
    __shared__ unsigned short Bbuf[4 * 128 * 8];
    __shared__ float s_inv[128], s_beta[128];
    __shared__ float s_w2[4 * 256];

    const int tid  = threadIdx.x;
    const int wave = tid >> 6, lane = tid & 63;
    const int quad = lane >> 4, l16 = lane & 15;
    const int sb   = blockIdx.x * 128;
    const int by   = blockIdx.y;
    const int head = by >> 1;
    const int lob  = (by & 1) * 128;
    const int b    = blockIdx.z;
    const int wm = (wave & 1) * 64, wn = (wave >> 1) * 64;

    const float* W  = (head == 0) ? w1c : (head == 1) ? w1l : w1t;
    const float* g  = (head == 0) ? gc  : (head == 1) ? gl  : gt;
    const float* bb = (head == 0) ? bc2 : (head == 1) ? bl  : bt;
    const float* mm = (head == 0) ? mc  : (head == 1) ? ml  : mt2;
    const float* vv = (head == 0) ? vc  : (head == 1) ? vl  : vt;
    const float* w2 = (head == 0) ? w2c : (head == 1) ? w2l : w2t;
    const float* wv = (head == 0) ? wvc : (head == 1) ? wvl : wvt;
    const int  CON  = (head == 0) ? 2 : (head == 1) ? 4 : 1;

    if (tid < 128) {
        int o = lob + tid;
        float iv = g[o] * rsqrtf(vv[o] + EPSF);
        s_inv[tid]  = iv;
        s_beta[tid] = bb[o] - mm[o] * iv;
    }
    for (int t = tid; t < CON * 256; t += 256) s_w2[t] = w2[t];

    const int sm = tid & 127;
    const int kh = tid >> 7;
    const unsigned short* Xb = feat + (size_t)b * C_ * OS2;
    const bool npred = (sb + sm) < OS2;

    f32x4 acc[4][4];
    #pragma unroll
    for (int i = 0; i < 4; ++i)
        #pragma unroll
        for (int j = 0; j < 4; ++j)
            acc[i][j] = (f32x4){0.f, 0.f, 0.f, 0.f};

    for (int kk = 0; kk < C_; kk += 32) {
        const float* wp = W + (size_t)(lob + sm) * C_ + kk + kh * 16;
        float4 w0 = *(const float4*)(wp + 0);
        float4 w1 = *(const float4*)(wp + 4);
        float4 w2v4 = *(const float4*)(wp + 8);
        float4 w3 = *(const float4*)(wp + 12);
        uint4 pa0, pa1;
        pa0.x = pk2(f2bf(w0.x), f2bf(w0.y)); pa0.y = pk2(f2bf(w0.z), f2bf(w0.w));
        pa0.z = pk2(f2bf(w1.x), f2bf(w1.y)); pa0.w = pk2(f2bf(w1.z), f2bf(w1.w));
        pa1.x = pk2(f2bf(w2v4.x), f2bf(w2v4.y)); pa1.y = pk2(f2bf(w2v4.z), f2bf(w2v4.w));
        pa1.z = pk2(f2bf(w3.x), f2bf(w3.y)); pa1.w = pk2(f2bf(w3.z), f2bf(w3.w));
        *(uint4*)&Abuf[((kh * 2 + 0) * 128 + sm) * 8] = pa0;
        *(uint4*)&Abuf[((kh * 2 + 1) * 128 + sm) * 8] = pa1;

        unsigned short bu[16];
        #pragma unroll
        for (int j = 0; j < 16; ++j)
            bu[j] = npred ? Xb[(size_t)(kk + kh * 16 + j) * OS2 + sb + sm]
                          : (unsigned short)0;
        uint4 pb0, pb1;
        pb0.x = pk2(bu[0],  bu[1]);  pb0.y = pk2(bu[2],  bu[3]);
        pb0.z = pk2(bu[4],  bu[5]);  pb0.w = pk2(bu[6],  bu[7]);
        pb1.x = pk2(bu[8],  bu[9]);  pb1.y = pk2(bu[10], bu[11]);
        pb1.z = pk2(bu[12], bu[13]); pb1.w = pk2(bu[14], bu[15]);
        *(uint4*)&Bbuf[((kh * 2 + 0) * 128 + sm) * 8] = pb0;
        *(uint4*)&Bbuf[((kh * 2 + 1) * 128 + sm) * 8] = pb1;

        __syncthreads();

        s16x8 af[4], bfr[4];
        #pragma unroll
        for (int mt = 0; mt < 4; ++mt)
            af[mt] = *(const s16x8*)&Abuf[(quad * 128 + wm + mt * 16 + l16) * 8];
        #pragma unroll
        for (int nt = 0; nt < 4; ++nt)
            bfr[nt] = *(const s16x8*)&Bbuf[(quad * 128 + wn + nt * 16 + l16) * 8];
        #pragma unroll
        for (int mt = 0; mt < 4; ++mt)
            #pragma unroll
            for (int nt = 0; nt < 4; ++nt)
                acc[mt][nt] = __builtin_amdgcn_mfma_f32_16x16x32_bf16(
                    af[mt], bfr[nt], acc[mt][nt], 0, 0, 0);

        __syncthreads();
    }

    // BN+ReLU in place
    #pragma unroll
    for (int mt = 0; mt < 4; ++mt)
        #pragma unroll
        for (int r = 0; r < 4; ++r) {
            int orow = wm + mt * 16 + quad * 4 + r;
            float iv = s_inv[orow], be = s_beta[orow];
            #pragma unroll
            for (int nt = 0; nt < 4; ++nt)
                acc[mt][nt][r] = fmaxf(acc[mt][nt][r] * iv + be, 0.f);
        }

    const float e0 = __expf(wv[0]), e1 = __expf(wv[1]), e2 = __expf(wv[2]);
    const float wi = ((si == 0) ? e0 : (si == 1) ? e1 : e2) / (e0 + e1 + e2);

    float* obase;
    if (head == 0)      obase = oacc + (size_t)b * 2 * OS2;
    else if (head == 1) obase = oacc + (size_t)B_ * 2 * OS2 + (size_t)b * 4 * OS2;
    else                obase = oacc + (size_t)B_ * 6 * OS2 + (size_t)b * OS2;

    for (int co = 0; co < CON; ++co) {
        float red[4] = {0.f, 0.f, 0.f, 0.f};
        #pragma unroll
        for (int mt = 0; mt < 4; ++mt)
            #pragma unroll
            for (int r = 0; r < 4; ++r) {
                float w2v = s_w2[co * 256 + lob + wm + mt * 16 + quad * 4 + r];
                #pragma unroll
                for (int nt = 0; nt < 4; ++nt)
                    red[nt] += w2v * acc[mt][nt][r];
            }
        #pragma unroll
        for (int nt = 0; nt < 4; ++nt) {
            red[nt] += __shfl_xor(red[nt], 16);
            red[nt] += __shfl_xor(red[nt], 32);
        }
        if (quad == 0) {
            #pragma unroll
            for (int nt = 0; nt < 4; ++nt) {
                int s = sb + wn + nt * 16 + l16;
                if (s < OS2)
                    atomicAdd(obase + (size_t)co * OS2 + s, wi * red[nt]);
            }
        }
    }
}

// ---------------------------------------------------------------------------
// Final bias add: out += sum_i softmax(w)[i] * b2[i][co], in place on d_out.
// ---------------------------------------------------------------------------
__global__ void bias_out(float* __restrict__ out,
    const float* __restrict__ cb2, const float* __restrict__ lb2,
    const float* __restrict__ tb2, const float* __restrict__ wvc,
    const float* __restrict__ wvl, const float* __restrict__ wvt)
{
    int n = blockIdx.x * 256 + threadIdx.x;
    if (n >= B_ * 7 * OS2) return;
    float bias;
    if (n < B_ * 2 * OS2) {
        float e0 = __expf(wvc[0]), e1 = __expf(wvc[1]), e2 = __expf(wvc[2]);
        int co = (n / OS2) & 1;
        bias = (e0 * cb2[co] + e1 * cb2[2 + co] + e2 * cb2[4 + co]) / (e0 + e1 + e2);
    } else if (n < B_ * 6 * OS2) {
        float e0 = __expf(wvl[0]), e1 = __expf(wvl[1]), e2 = __expf(wvl[2]);
        int co = ((n - B_ * 2 * OS2) / OS2) & 3;
        bias = (e0 * lb2[co] + e1 * lb2[4 + co] + e2 * lb2[8 + co]) / (e0 + e1 + e2);
    } else {
        float e0 = __expf(wvt[0]), e1 = __expf(wvt[1]), e2 = __expf(wvt[2]);
        bias = (e0 * tb2[0] + e1 * tb2[1] + e2 * tb2[2]) / (e0 + e1 + e2);
    }
    out[n] += bias;
}

__global__ void fillf_k(float* __restrict__ out, int n, float v)
{
    int i = blockIdx.x * 256 + threadIdx.x;
    if (i < n) out[i] = v;
}

// ===========================================================================
extern "C" void kernel_launch(void* const* d_in, const int* in_sizes, int n_in,
                              void* d_out, int out_size, void* d_ws, size_t ws_size,
                              hipStream_t stream)
{
    static const int EXP_SIZES[36] = {
        2408448, 47235072, 6912,
        768, 768, 768, 768,
        196608, 768, 768, 768, 768,
        196608, 768, 768, 768, 768, 1536, 6,
        196608, 768, 768, 768, 768, 3072, 12,
        196608, 768, 768, 768, 768, 768, 3,
        3, 3, 3
    };
    int bad = -1;
    if (n_in != 36) bad = 99;
    else {
        for (int i = 0; i < 36; ++i)
            if (in_sizes[i] != EXP_SIZES[i]) { bad = i; break; }
    }
    if (bad < 0 && ws_size < (size_t)40960000) bad = 90;
    if (bad < 0 && out_size != 280000) bad = 95;
    if (bad >= 0) {
        fillf_k<<<(out_size + 255) / 256, 256, 0, stream>>>(
            (float*)d_out, out_size, 500.f + 4.f * bad);
        return;
    }

    const float* z_fs   = (const float*)d_in[0];
    const float* x_fs   = (const float*)d_in[1];
    const float* pre_w  = (const float*)d_in[2];
    const float* pre_g  = (const float*)d_in[3];
    const float* pre_b  = (const float*)d_in[4];
    const float* pre_m  = (const float*)d_in[5];
    const float* pre_v  = (const float*)d_in[6];
    const float* head_w = (const float*)d_in[7];
    const float* head_g = (const float*)d_in[8];
    const float* head_b = (const float*)d_in[9];
    const float* head_m = (const float*)d_in[10];
    const float* head_v = (const float*)d_in[11];
    const float* cls_w1 = (const float*)d_in[12];
    const float* cls_g  = (const float*)d_in[13];
    const float* cls_b  = (const float*)d_in[14];
    const float* cls_m  = (const float*)d_in[15];
    const float* cls_v  = (const float*)d_in[16];
    const float* cls_w2 = (const float*)d_in[17];
    const float* cls_b2 = (const float*)d_in[18];
    const float* loc_w1 = (const float*)d_in[19];
    const float* loc_g  = (const float*)d_in[20];
    const float* loc_b  = (const float*)d_in[21];
    const float* loc_m  = (const float*)d_in[22];
    const float* loc_v  = (const float*)d_in[23];
    const float* loc_w2 = (const float*)d_in[24];
    const float* loc_b2 = (const float*)d_in[25];
    const float* ctr_w1 = (const float*)d_in[26];
    const float* ctr_g  = (const float*)d_in[27];
    const float* ctr_b  = (const float*)d_in[28];
    const float* ctr_m  = (const float*)d_in[29];
    const float* ctr_v  = (const float*)d_in[30];
    const float* ctr_w2 = (const float*)d_in[31];
    const float* ctr_b2 = (const float*)d_in[32];
    const float* w_cls  = (const float*)d_in[33];
    const float* w_loc  = (const float*)d_in[34];
    const float* w_ctr  = (const float*)d_in[35];

    // workspace: xc bf16 (20.48 MB) | feat bf16 (20.48 MB)
    unsigned short* xc   = (unsigned short*)d_ws;
    unsigned short* feat = xc + (size_t)B_ * C_ * OS2;
    const int OUT_N = B_ * 7 * OS2;   // 280,000

    hipMemsetAsync(d_out, 0, (size_t)OUT_N * sizeof(float), stream);

    for (int i = 0; i < 3; ++i) {
        fused_pre_xcorr<<<B_ * C_, 256, 0, stream>>>(
            x_fs + (size_t)i * B_ * C_ * XS * XS,
            z_fs + (size_t)i * B_ * C_ * ZS * ZS,
            pre_w + (size_t)i * C_ * 9,
            pre_g + i * C_, pre_b + i * C_, pre_m + i * C_, pre_v + i * C_,
            xc);

        c1_mfma<<<dim3(5, 2, B_), 256, 0, stream>>>(
            xc, head_w + (size_t)i * HD_ * C_,
            head_g + i * HD_, head_b + i * HD_, head_m + i * HD_, head_v + i * HD_,
            feat);

        heads3_mfma<<<dim3(5, 6, B_), 256, 0, stream>>>(
            feat,
            cls_w1 + (size_t)i * HD_ * HD_, loc_w1 + (size_t)i * HD_ * HD_,
            ctr_w1 + (size_t)i * HD_ * HD_,
            cls_g + i * HD_, cls_b + i * HD_, cls_m + i * HD_, cls_v + i * HD_,
            loc_g + i * HD_, loc_b + i * HD_, loc_m + i * HD_, loc_v + i * HD_,
            ctr_g + i * HD_, ctr_b + i * HD_, ctr_m + i * HD_, ctr_v + i * HD_,
            cls_w2 + (size_t)i * 2 * HD_, loc_w2 + (size_t)i * 4 * HD_,
            ctr_w2 + (size_t)i * 1 * HD_,
            w_cls, w_loc, w_ctr, i, (float*)d_out);
    }

    bias_out<<<(OUT_N + 255) / 256, 256, 0, stream>>>(
        (float*)d_out, cls_b2, loc_b2, ctr_b2, w_cls, w_loc, w_ctr);
}